// Round 1
// baseline (656.140 us; speedup 1.0000x reference)
//
#include <hip/hip_runtime.h>

// ---------------- problem constants (from reference) ----------------
#define T_TOK 8192
#define K_DIM 4096
#define N_DIM 4096
#define G_NUM 8
#define R_DIM 64

#define BM 128
#define BN 128
#define BK 64

typedef __attribute__((ext_vector_type(8))) short bfrag;   // 8 x bf16 (4 VGPR)
typedef __attribute__((ext_vector_type(4))) float f32x4;   // MFMA C/D

__device__ __forceinline__ unsigned short f2bf(float f) {
  unsigned int u = __float_as_uint(f);
  u += 0x7fffu + ((u >> 16) & 1u);           // RNE
  return (unsigned short)(u >> 16);
}

__device__ __forceinline__ void gload_lds16(const void* g, void* l) {
  __builtin_amdgcn_global_load_lds(
      (const __attribute__((address_space(1))) void*)g,
      (__attribute__((address_space(3))) void*)l, 16, 0, 0);
}

// Stage a [ROWS x 64] bf16 tile (logical row-major, 128B rows) into LDS.
// LDS dest is LINEAR (global_load_lds requirement, rule #21); the global
// SOURCE is pre-swizzled with the same involution the reader applies:
//   16B-slot' = slot ^ (row & 7)
// NCHUNKS = ROWS*8/256 (256 threads, 16B per chunk).
template<int NCHUNKS>
__device__ __forceinline__ void stage_tile(short* lds, const unsigned short* gsrc,
                                           long row_stride, int tid) {
#pragma unroll
  for (int i = 0; i < NCHUNKS; ++i) {
    int c = i * 256 + tid;
    int row = c >> 3;                  // 8 chunks of 16B per 128B row
    int col16 = (c & 7) ^ (row & 7);   // pre-swizzled source slot
    gload_lds16(gsrc + (long)row * row_stride + col16 * 8, lds + c * 8);
  }
}

// Swizzled fragment read: logical (row, kbyte) -> physical LDS byte.
__device__ __forceinline__ bfrag read_frag(const short* lds, int row, int kbyte) {
  int byte = (row << 7) + kbyte;
  byte ^= (row & 7) << 4;
  return *(const bfrag*)((const char*)lds + byte);
}

// ---------------- fp32 -> bf16 convert (vectorized) ----------------
__global__ __launch_bounds__(256) void cvt_f32_bf16(const float* __restrict__ src,
                                                    unsigned short* __restrict__ dst,
                                                    long n4) {
  long i = (long)blockIdx.x * blockDim.x + threadIdx.x;
  long stride = (long)gridDim.x * blockDim.x;
  for (; i < n4; i += stride) {
    float4 v = ((const float4*)src)[i];
    ushort4 o;
    o.x = f2bf(v.x); o.y = f2bf(v.y); o.z = f2bf(v.z); o.w = f2bf(v.w);
    ((ushort4*)dst)[i] = o;
  }
}

// lora_b [g][r][n] fp32  ->  Bt [g][n][r] bf16   (so expand-B frags are r-contiguous)
__global__ __launch_bounds__(256) void transpose_b(const float* __restrict__ lb,
                                                   unsigned short* __restrict__ bt) {
  __shared__ float tile[64][65];
  int g = blockIdx.y;
  long n0 = (long)blockIdx.x * 64;
  for (int i = threadIdx.x; i < 64 * 64; i += 256) {
    int r = i >> 6, n = i & 63;
    tile[r][n] = lb[((long)g * R_DIM + r) * N_DIM + n0 + n];
  }
  __syncthreads();
  for (int i = threadIdx.x; i < 64 * 64; i += 256) {
    int n = i >> 6, r = i & 63;
    bt[((long)g * N_DIM + n0 + n) * R_DIM + r] = f2bf(tile[r][n]);
  }
}

// ---------------- shrink: S[t][r] = x[t] @ lora_a[g]^T ----------------
__global__ __launch_bounds__(256) void shrink_kernel(const unsigned short* __restrict__ xb,
                                                     const unsigned short* __restrict__ Ab,
                                                     const int* __restrict__ glist,
                                                     unsigned short* __restrict__ S) {
  __shared__ short sA[BM * BK];     // 128 x 64
  __shared__ short sB[R_DIM * BK];  // 64 x 64
  int row0 = blockIdx.x * BM;
  int tid = threadIdx.x;
  int w = tid >> 6, l = tid & 63;
  int wm = (w >> 1) * 64, wn = (w & 1) * 32;
  int g = 0;
#pragma unroll
  for (int i = 0; i < G_NUM; ++i) g += (row0 >= glist[i]);

  int lrow = l & 15, lk = (l >> 4) * 16;
  f32x4 acc[4][2] = {};

  for (int kt = 0; kt < K_DIM / BK; ++kt) {
    stage_tile<4>(sA, xb + (long)row0 * K_DIM + kt * BK, K_DIM, tid);
    stage_tile<2>(sB, Ab + (long)g * R_DIM * K_DIM + kt * BK, K_DIM, tid);
    __syncthreads();
#pragma unroll
    for (int ks = 0; ks < 2; ++ks) {
      bfrag a[4], b[2];
#pragma unroll
      for (int mi = 0; mi < 4; ++mi) a[mi] = read_frag(sA, wm + mi * 16 + lrow, ks * 64 + lk);
#pragma unroll
      for (int ni = 0; ni < 2; ++ni) b[ni] = read_frag(sB, wn + ni * 16 + lrow, ks * 64 + lk);
#pragma unroll
      for (int mi = 0; mi < 4; ++mi)
#pragma unroll
        for (int ni = 0; ni < 2; ++ni)
          acc[mi][ni] = __builtin_amdgcn_mfma_f32_16x16x32_bf16(a[mi], b[ni], acc[mi][ni], 0, 0, 0);
    }
    __syncthreads();
  }

#pragma unroll
  for (int mi = 0; mi < 4; ++mi) {
    int r0 = row0 + wm + mi * 16 + ((l >> 4) << 2);
#pragma unroll
    for (int ni = 0; ni < 2; ++ni) {
      int c = wn + ni * 16 + (l & 15);
      f32x4 v = acc[mi][ni];
#pragma unroll
      for (int r = 0; r < 4; ++r) S[(long)(r0 + r) * R_DIM + c] = f2bf(v[r]);
    }
  }
}

// ---------------- main: out = x@W^T + S@Bt[g] (fused extra K-step) ----------------
__global__ __launch_bounds__(256) void gemm_main(const unsigned short* __restrict__ xb,
                                                 const unsigned short* __restrict__ Wb,
                                                 const unsigned short* __restrict__ S,
                                                 const unsigned short* __restrict__ Bt,
                                                 const int* __restrict__ glist,
                                                 float* __restrict__ out) {
  __shared__ short sA[BM * BK];
  __shared__ short sB[BN * BK];
  // XCD-bijective swizzle: 2048 blocks, 8 XCDs, 256 per XCD
  int bid = blockIdx.x;
  int wg = (bid & 7) * ((T_TOK / BM) * (N_DIM / BN) / 8) + (bid >> 3);
  int tm = wg >> 5;       // / (N_DIM/BN = 32)
  int tn = wg & 31;
  int row0 = tm * BM, col0 = tn * BN;
  int tid = threadIdx.x;
  int w = tid >> 6, l = tid & 63;
  int wm = (w >> 1) * 64, wn = (w & 1) * 64;
  int g = 0;
#pragma unroll
  for (int i = 0; i < G_NUM; ++i) g += (row0 >= glist[i]);

  int lrow = l & 15, lk = (l >> 4) * 16;
  f32x4 acc[4][4] = {};

  for (int kt = 0; kt < K_DIM / BK; ++kt) {
    stage_tile<4>(sA, xb + (long)row0 * K_DIM + kt * BK, K_DIM, tid);
    stage_tile<4>(sB, Wb + (long)col0 * K_DIM + kt * BK, K_DIM, tid);
    __syncthreads();
#pragma unroll
    for (int ks = 0; ks < 2; ++ks) {
      bfrag a[4], b[4];
#pragma unroll
      for (int mi = 0; mi < 4; ++mi) a[mi] = read_frag(sA, wm + mi * 16 + lrow, ks * 64 + lk);
#pragma unroll
      for (int ni = 0; ni < 4; ++ni) b[ni] = read_frag(sB, wn + ni * 16 + lrow, ks * 64 + lk);
#pragma unroll
      for (int mi = 0; mi < 4; ++mi)
#pragma unroll
        for (int ni = 0; ni < 4; ++ni)
          acc[mi][ni] = __builtin_amdgcn_mfma_f32_16x16x32_bf16(a[mi], b[ni], acc[mi][ni], 0, 0, 0);
    }
    __syncthreads();
  }

  // LoRA expand as one extra K-step: A = S[row0.., 0..63], B = Bt[g][col0..][0..63]
  stage_tile<4>(sA, S + (long)row0 * R_DIM, R_DIM, tid);
  stage_tile<4>(sB, Bt + ((long)g * N_DIM + col0) * R_DIM, R_DIM, tid);
  __syncthreads();
#pragma unroll
  for (int ks = 0; ks < 2; ++ks) {
    bfrag a[4], b[4];
#pragma unroll
    for (int mi = 0; mi < 4; ++mi) a[mi] = read_frag(sA, wm + mi * 16 + lrow, ks * 64 + lk);
#pragma unroll
    for (int ni = 0; ni < 4; ++ni) b[ni] = read_frag(sB, wn + ni * 16 + lrow, ks * 64 + lk);
#pragma unroll
    for (int mi = 0; mi < 4; ++mi)
#pragma unroll
      for (int ni = 0; ni < 4; ++ni)
        acc[mi][ni] = __builtin_amdgcn_mfma_f32_16x16x32_bf16(a[mi], b[ni], acc[mi][ni], 0, 0, 0);
  }

  // C-write (fp32): col = lane&15, row = (lane>>4)*4 + reg   [m89-verified]
#pragma unroll
  for (int mi = 0; mi < 4; ++mi) {
    int r0 = row0 + wm + mi * 16 + ((l >> 4) << 2);
#pragma unroll
    for (int ni = 0; ni < 4; ++ni) {
      int c = col0 + wn + ni * 16 + (l & 15);
      f32x4 v = acc[mi][ni];
#pragma unroll
      for (int r = 0; r < 4; ++r) out[(long)(r0 + r) * N_DIM + c] = v[r];
    }
  }
}

// ---------------- launcher ----------------
extern "C" void kernel_launch(void* const* d_in, const int* in_sizes, int n_in,
                              void* d_out, int out_size, void* d_ws, size_t ws_size,
                              hipStream_t stream) {
  (void)in_sizes; (void)n_in; (void)out_size; (void)ws_size;
  const float* x  = (const float*)d_in[0];   // [T, K]
  const float* W  = (const float*)d_in[1];   // [N, K]
  const float* la = (const float*)d_in[2];   // [9, R, K]
  const float* lb = (const float*)d_in[3];   // [9, R, N]
  const int*   gl = (const int*)d_in[4];     // [G] cumulative ends
  float* out = (float*)d_out;

  char* ws = (char*)d_ws;
  unsigned short* xb = (unsigned short*)(ws);                 // 64 MiB
  unsigned short* Wb = (unsigned short*)(ws + 67108864);      // 32 MiB
  unsigned short* Ab = (unsigned short*)(ws + 100663296);     // 4 MiB
  unsigned short* Bt = (unsigned short*)(ws + 104857600);     // 4 MiB
  unsigned short* S  = (unsigned short*)(ws + 109051904);     // 1 MiB

  cvt_f32_bf16<<<2048, 256, 0, stream>>>(x,  xb, (long)T_TOK * K_DIM / 4);
  cvt_f32_bf16<<<2048, 256, 0, stream>>>(W,  Wb, (long)N_DIM * K_DIM / 4);
  cvt_f32_bf16<<<512,  256, 0, stream>>>(la, Ab, (long)G_NUM * R_DIM * K_DIM / 4);
  transpose_b<<<dim3(N_DIM / 64, G_NUM), 256, 0, stream>>>(lb, Bt);
  shrink_kernel<<<T_TOK / BM, 256, 0, stream>>>(xb, Ab, gl, S);
  gemm_main<<<(T_TOK / BM) * (N_DIM / BN), 256, 0, stream>>>(xb, Wb, S, Bt, gl, out);
}

// Round 2
// 527.754 us; speedup vs baseline: 1.2433x; 1.2433x over previous
//
#include <hip/hip_runtime.h>

// ---------------- problem constants ----------------
#define T_TOK 8192
#define K_DIM 4096
#define N_DIM 4096
#define G_NUM 8
#define R_DIM 64

typedef __attribute__((ext_vector_type(8))) short bfrag;   // 8 x bf16
typedef __attribute__((ext_vector_type(4))) float f32x4;

__device__ __forceinline__ unsigned short f2bf(float f) {
  unsigned int u = __float_as_uint(f);
  u += 0x7fffu + ((u >> 16) & 1u);
  return (unsigned short)(u >> 16);
}
__device__ __forceinline__ float bf2f(unsigned short u) {
  return __uint_as_float((unsigned int)u << 16);
}

__device__ __forceinline__ void gload_lds16(const void* g, void* l) {
  __builtin_amdgcn_global_load_lds(
      (const __attribute__((address_space(1))) void*)g,
      (__attribute__((address_space(3))) void*)l, 16, 0, 0);
}

// Swizzled fragment read from a [rows x 64] bf16 tile stored as 16KiB halves.
// physical byte = (row&127)*128 + half*16384 + (kbyte ^ ((row&7)<<4))
__device__ __forceinline__ bfrag rf(const short* base, int row, int kbyte) {
  int byte = ((row & 127) << 7) + ((row >> 7) << 14) + (kbyte ^ ((row & 7) << 4));
  return *(const bfrag*)((const char*)base + byte);
}

// Stage one 128x64 bf16 half-tile (row-major, stride elements) into linear LDS,
// pre-swizzling the GLOBAL source (rule #21): slot' = slot ^ (row&7).
// 1024 chunks of 16B, 512 threads -> 2 loads/thread.
__device__ __forceinline__ void stage_half(short* ldsdst, const unsigned short* gsrc,
                                           long stride, int tid) {
#pragma unroll
  for (int i = 0; i < 2; ++i) {
    int c = i * 512 + tid;
    int row = c >> 3;
    int slot = (c & 7) ^ (row & 7);
    gload_lds16(gsrc + (long)row * stride + slot * 8, ldsdst + c * 8);
  }
}

// ---------------- fp32 -> bf16 convert ----------------
__global__ __launch_bounds__(256) void cvt_f32_bf16(const float* __restrict__ src,
                                                    unsigned short* __restrict__ dst,
                                                    long n4) {
  long i = (long)blockIdx.x * blockDim.x + threadIdx.x;
  long stride = (long)gridDim.x * blockDim.x;
  for (; i < n4; i += stride) {
    float4 v = ((const float4*)src)[i];
    ushort4 o;
    o.x = f2bf(v.x); o.y = f2bf(v.y); o.z = f2bf(v.z); o.w = f2bf(v.w);
    ((ushort4*)dst)[i] = o;
  }
}

// lora_b [g][r][n] fp32 -> Bt [g][n][r] bf16
__global__ __launch_bounds__(256) void transpose_b(const float* __restrict__ lb,
                                                   unsigned short* __restrict__ bt) {
  __shared__ float tile[64][65];
  int g = blockIdx.y;
  long n0 = (long)blockIdx.x * 64;
  for (int i = threadIdx.x; i < 64 * 64; i += 256) {
    int r = i >> 6, n = i & 63;
    tile[r][n] = lb[((long)g * R_DIM + r) * N_DIM + n0 + n];
  }
  __syncthreads();
  for (int i = threadIdx.x; i < 64 * 64; i += 256) {
    int n = i >> 6, r = i & 63;
    bt[((long)g * N_DIM + n0 + n) * R_DIM + r] = f2bf(tile[r][n]);
  }
}

// ---------------- fused: cvt x -> xb  AND  partial shrink S ----------------
// grid (T/128, 4 K-splits); block 256. Each block: rows r0..r0+127, K-slice by*1024.
__global__ __launch_bounds__(256) void fused_x_shrink(const float* __restrict__ x,
    const unsigned short* __restrict__ Ab, const int* __restrict__ glist,
    unsigned short* __restrict__ xb, unsigned short* __restrict__ Spart) {
  __shared__ short sX[8192];   // 128x64 bf16, swizzled
  __shared__ short sAa[4096];  // 64x64 bf16, swizzled
  int r0 = blockIdx.x * 128;
  long ks0 = (long)blockIdx.y * 1024;
  int tid = threadIdx.x;
  int w = tid >> 6, l = tid & 63;
  int wm = w * 32;
  int lrow = l & 15, kb = (l >> 4) * 16;
  int g = 0;
#pragma unroll
  for (int i = 0; i < G_NUM; ++i) g += (r0 >= glist[i]);
  f32x4 acc[2][4] = {};

  for (int kt = 0; kt < 16; ++kt) {
    long kbase = ks0 + kt * 64;
    // load fp32 x, cvt, write xb, ds_write swizzled
#pragma unroll
    for (int it = 0; it < 8; ++it) {
      int c = it * 256 + tid;
      int row = c >> 4, fc = c & 15;          // 16 float4 per 64-col row
      float4 v = *(const float4*)(x + (long)(r0 + row) * K_DIM + kbase + fc * 4);
      ushort4 o; o.x = f2bf(v.x); o.y = f2bf(v.y); o.z = f2bf(v.z); o.w = f2bf(v.w);
      *(ushort4*)(xb + (long)(r0 + row) * K_DIM + kbase + fc * 4) = o;
      int pbyte = (row << 7) + ((((fc >> 1) ^ (row & 7)) << 4)) + ((fc & 1) << 3);
      *(ushort4*)((char*)sX + pbyte) = o;
    }
    // stage lora-A 64x64 tile (pre-swizzled source)
#pragma unroll
    for (int i = 0; i < 2; ++i) {
      int c = i * 256 + tid;
      int row = c >> 3, slot = (c & 7) ^ (row & 7);
      gload_lds16(Ab + ((long)g * R_DIM + row) * K_DIM + kbase + slot * 8, sAa + c * 8);
    }
    __syncthreads();
#pragma unroll
    for (int mi = 0; mi < 2; ++mi)
#pragma unroll
      for (int ni = 0; ni < 4; ++ni)
#pragma unroll
        for (int ks = 0; ks < 2; ++ks)
          acc[mi][ni] = __builtin_amdgcn_mfma_f32_16x16x32_bf16(
              rf(sX, wm + mi * 16 + lrow, ks * 64 + kb),
              rf(sAa, ni * 16 + lrow, ks * 64 + kb), acc[mi][ni], 0, 0, 0);
    __syncthreads();
  }
#pragma unroll
  for (int mi = 0; mi < 2; ++mi) {
    int rr = wm + mi * 16 + ((l >> 4) << 2);
#pragma unroll
    for (int ni = 0; ni < 4; ++ni) {
      int cc = ni * 16 + (l & 15);
      f32x4 v = acc[mi][ni];
#pragma unroll
      for (int r = 0; r < 4; ++r)
        Spart[((long)blockIdx.y * T_TOK + r0 + rr + r) * R_DIM + cc] = f2bf(v[r]);
    }
  }
}

// sum 4 bf16 partials -> bf16 S
__global__ __launch_bounds__(256) void reduce_S(const unsigned short* __restrict__ Spart,
                                                unsigned short* __restrict__ S) {
  long i = (long)blockIdx.x * 256 + threadIdx.x;   // ushort4 index, grid sized exactly
  float s0 = 0, s1 = 0, s2 = 0, s3 = 0;
#pragma unroll
  for (int p = 0; p < 4; ++p) {
    ushort4 v = ((const ushort4*)(Spart + (long)p * T_TOK * R_DIM))[i];
    s0 += bf2f(v.x); s1 += bf2f(v.y); s2 += bf2f(v.z); s3 += bf2f(v.w);
  }
  ushort4 o; o.x = f2bf(s0); o.y = f2bf(s1); o.z = f2bf(s2); o.w = f2bf(s3);
  ((ushort4*)S)[i] = o;
}

// ---------------- main GEMM: 256x256 tile, BK=64, 8-phase counted-vmcnt ----------------
// 8 waves (2M x 4N), per-wave 128x64 out. LDS 128KiB = 2 bufs x (A:2 halves + B:2 halves).
// Steady-state staging (1 half-tile = 2 loads/thread per phase), vmcnt(4) at P4/P8:
//   P1: b1-A0<-t1   P2: b1-A1<-t1   P3: b0-B0<-t0+2  P4: b0-B1<-t0+2 [vm4]
//   P5: b0-A0<-t0+2 P6: b0-A1<-t0+2 P7: b1-B0<-t1+2  P8: b1-B1<-t1+2 [vm4]
// Quadrant order per tile: (0,0)(0,1)(1,1)(1,0) -> A read P1,P3; B read P1,P2.
// Every stage targets a region whose last reader phase is already barrier-closed.
__global__ __launch_bounds__(512, 2) void gemm256(const unsigned short* __restrict__ xb,
    const unsigned short* __restrict__ Wb, const unsigned short* __restrict__ Sb,
    const unsigned short* __restrict__ Bt, const int* __restrict__ glist,
    float* __restrict__ out) {
  __shared__ short lds[65536];   // 128 KiB
  int bid = blockIdx.x;
  int wg = (bid & 7) * 64 + (bid >> 3);    // XCD-bijective (512 % 8 == 0)
  int tm = wg >> 4, tn = wg & 15;
  long row0 = (long)tm * 256, col0 = (long)tn * 256;
  int tid = threadIdx.x;
  int w = tid >> 6, l = tid & 63;
  int wm = (w >> 2) * 128, wn = (w & 3) * 64;
  int lrow = l & 15, kb = (l >> 4) * 16;
  int g = 0;
#pragma unroll
  for (int i = 0; i < G_NUM; ++i) g += (row0 >= glist[i]);

  const unsigned short* Abase = xb + row0 * K_DIM;
  const unsigned short* Bbase = Wb + col0 * K_DIM;

  auto stA = [&](int t, int b, int h) {
    stage_half(lds + b * 32768 + h * 8192,
               Abase + (long)h * 128 * K_DIM + (long)(t & 63) * 64, K_DIM, tid);
  };
  auto stB = [&](int t, int b, int h) {
    stage_half(lds + b * 32768 + 16384 + h * 8192,
               Bbase + (long)h * 128 * K_DIM + (long)(t & 63) * 64, K_DIM, tid);
  };
  auto ldA = [&](int b, int mi, int ks) {
    return rf(lds + b * 32768, wm + mi * 16 + lrow, ks * 64 + kb);
  };
  auto ldB = [&](int b, int ni, int ks) {
    return rf(lds + b * 32768 + 16384, wn + ni * 16 + lrow, ks * 64 + kb);
  };

  f32x4 acc[8][4] = {};
  auto MFMAQ = [&](bfrag (&a)[4][2], bfrag (&b)[2][2], int mi0, int ni0) {
#pragma unroll
    for (int mi = 0; mi < 4; ++mi)
#pragma unroll
      for (int ni = 0; ni < 2; ++ni)
#pragma unroll
        for (int ks = 0; ks < 2; ++ks)
          acc[mi0 + mi][ni0 + ni] = __builtin_amdgcn_mfma_f32_16x16x32_bf16(
              a[mi][ks], b[ni][ks], acc[mi0 + mi][ni0 + ni], 0, 0, 0);
  };

#define SYNC_IN()  do { __builtin_amdgcn_s_barrier(); \
  asm volatile("s_waitcnt lgkmcnt(0)" ::: "memory"); \
  __builtin_amdgcn_sched_barrier(0); } while (0)
#define PRIO1() __builtin_amdgcn_s_setprio(1)
#define PRIO0() __builtin_amdgcn_s_setprio(0)
#define BAR()   __builtin_amdgcn_s_barrier()
#define VM4()   asm volatile("s_waitcnt vmcnt(4)" ::: "memory")

  // prologue: tile0 -> buf0 full; tile1 -> buf1 B halves
  stA(0, 0, 0); stA(0, 0, 1); stB(0, 0, 0); stB(0, 0, 1);
  stB(1, 1, 0); stB(1, 1, 1);
  VM4();
  BAR();

  bfrag aL[4][2], aH[4][2], bL[2][2], bH[2][2];

  for (int it = 0; it < 32; ++it) {
    int t0 = 2 * it, t1 = 2 * it + 1;
    // ---------- tile t0 from buf0 ----------
    // P1: Q(0,0)
#pragma unroll
    for (int mi = 0; mi < 4; ++mi) { aL[mi][0] = ldA(0, mi, 0); aL[mi][1] = ldA(0, mi, 1); }
#pragma unroll
    for (int ni = 0; ni < 2; ++ni) { bL[ni][0] = ldB(0, ni, 0); bL[ni][1] = ldB(0, ni, 1); }
    stA(t1, 1, 0);
    SYNC_IN(); PRIO1(); MFMAQ(aL, bL, 0, 0); PRIO0(); BAR();
    // P2: Q(0,1)
#pragma unroll
    for (int ni = 0; ni < 2; ++ni) { bH[ni][0] = ldB(0, ni + 2, 0); bH[ni][1] = ldB(0, ni + 2, 1); }
    stA(t1, 1, 1);
    SYNC_IN(); PRIO1(); MFMAQ(aL, bH, 0, 2); PRIO0(); BAR();
    // P3: Q(1,1)
#pragma unroll
    for (int mi = 0; mi < 4; ++mi) { aH[mi][0] = ldA(0, mi + 4, 0); aH[mi][1] = ldA(0, mi + 4, 1); }
    stB(t0 + 2, 0, 0);
    SYNC_IN(); PRIO1(); MFMAQ(aH, bH, 4, 2); PRIO0(); BAR();
    // P4: Q(1,0) — no new ds_reads
    stB(t0 + 2, 0, 1);
    SYNC_IN(); PRIO1(); MFMAQ(aH, bL, 4, 0); PRIO0();
    VM4();
    BAR();
    // ---------- tile t1 from buf1 ----------
    // P5: Q(0,0)
#pragma unroll
    for (int mi = 0; mi < 4; ++mi) { aL[mi][0] = ldA(1, mi, 0); aL[mi][1] = ldA(1, mi, 1); }
#pragma unroll
    for (int ni = 0; ni < 2; ++ni) { bL[ni][0] = ldB(1, ni, 0); bL[ni][1] = ldB(1, ni, 1); }
    stA(t0 + 2, 0, 0);
    SYNC_IN(); PRIO1(); MFMAQ(aL, bL, 0, 0); PRIO0(); BAR();
    // P6: Q(0,1)
#pragma unroll
    for (int ni = 0; ni < 2; ++ni) { bH[ni][0] = ldB(1, ni + 2, 0); bH[ni][1] = ldB(1, ni + 2, 1); }
    stA(t0 + 2, 0, 1);
    SYNC_IN(); PRIO1(); MFMAQ(aL, bH, 0, 2); PRIO0(); BAR();
    // P7: Q(1,1)
#pragma unroll
    for (int mi = 0; mi < 4; ++mi) { aH[mi][0] = ldA(1, mi + 4, 0); aH[mi][1] = ldA(1, mi + 4, 1); }
    stB(t1 + 2, 1, 0);
    SYNC_IN(); PRIO1(); MFMAQ(aH, bH, 4, 2); PRIO0(); BAR();
    // P8: Q(1,0)
    stB(t1 + 2, 1, 1);
    SYNC_IN(); PRIO1(); MFMAQ(aH, bL, 4, 0); PRIO0();
    VM4();
    BAR();
  }

  // ---------- LoRA expand tail: one extra K-step (R=64) ----------
  asm volatile("s_waitcnt vmcnt(0)" ::: "memory");  // drain wrap-around prefetches
  BAR();
  {
    const unsigned short* Sg  = Sb + row0 * R_DIM;
    const unsigned short* Btg = Bt + ((long)g * N_DIM + col0) * R_DIM;
#pragma unroll
    for (int i = 0; i < 4; ++i) {               // S tile 256x64 -> lds[0..]
      int c = i * 512 + tid;
      int row = c >> 3, slot = (c & 7) ^ (row & 7);
      gload_lds16(Sg + (long)row * R_DIM + slot * 8, lds + c * 8);
    }
#pragma unroll
    for (int i = 0; i < 4; ++i) {               // Bt tile 256x64 -> lds[16384..]
      int c = i * 512 + tid;
      int row = c >> 3, slot = (c & 7) ^ (row & 7);
      gload_lds16(Btg + (long)row * R_DIM + slot * 8, lds + 16384 + c * 8);
    }
    asm volatile("s_waitcnt vmcnt(0)" ::: "memory");
    BAR();
#pragma unroll
    for (int mi = 0; mi < 8; ++mi)
#pragma unroll
      for (int ni = 0; ni < 4; ++ni)
#pragma unroll
        for (int ks = 0; ks < 2; ++ks)
          acc[mi][ni] = __builtin_amdgcn_mfma_f32_16x16x32_bf16(
              rf(lds, wm + mi * 16 + lrow, ks * 64 + kb),
              rf(lds + 16384, wn + ni * 16 + lrow, ks * 64 + kb), acc[mi][ni], 0, 0, 0);
  }

  // ---------- C write ----------
#pragma unroll
  for (int mi = 0; mi < 8; ++mi) {
    long rr = row0 + wm + mi * 16 + ((l >> 4) << 2);
#pragma unroll
    for (int ni = 0; ni < 4; ++ni) {
      long cc = col0 + wn + ni * 16 + (l & 15);
      f32x4 v = acc[mi][ni];
#pragma unroll
      for (int r = 0; r < 4; ++r) out[(rr + r) * N_DIM + cc] = v[r];
    }
  }
#undef SYNC_IN
#undef PRIO1
#undef PRIO0
#undef BAR
#undef VM4
}

// ---------------- launcher ----------------
extern "C" void kernel_launch(void* const* d_in, const int* in_sizes, int n_in,
                              void* d_out, int out_size, void* d_ws, size_t ws_size,
                              hipStream_t stream) {
  (void)in_sizes; (void)n_in; (void)out_size; (void)ws_size;
  const float* x  = (const float*)d_in[0];
  const float* W  = (const float*)d_in[1];
  const float* la = (const float*)d_in[2];
  const float* lb = (const float*)d_in[3];
  const int*   gl = (const int*)d_in[4];
  float* out = (float*)d_out;

  char* ws = (char*)d_ws;
  unsigned short* xb    = (unsigned short*)(ws);                 // 64 MiB
  unsigned short* Wb    = (unsigned short*)(ws + 67108864);      // 32 MiB
  unsigned short* Ab    = (unsigned short*)(ws + 100663296);     // 4 MiB
  unsigned short* Bt    = (unsigned short*)(ws + 104857600);     // 4 MiB
  unsigned short* S     = (unsigned short*)(ws + 109051904);     // 1 MiB
  unsigned short* Spart = (unsigned short*)(ws + 110100480);     // 4 MiB

  cvt_f32_bf16<<<512, 256, 0, stream>>>(la, Ab, (long)G_NUM * R_DIM * K_DIM / 4);
  cvt_f32_bf16<<<2048, 256, 0, stream>>>(W, Wb, (long)N_DIM * K_DIM / 4);
  transpose_b<<<dim3(N_DIM / 64, G_NUM), 256, 0, stream>>>(lb, Bt);
  fused_x_shrink<<<dim3(T_TOK / 128, 4), 256, 0, stream>>>(x, Ab, gl, xb, Spart);
  reduce_S<<<512, 256, 0, stream>>>(Spart, S);
  gemm256<<<512, 512, 0, stream>>>(xb, Wb, S, Bt, gl, out);
}